// Round 1
// 663.429 us; speedup vs baseline: 1.1192x; 1.1192x over previous
//
#include <hip/hip_runtime.h>
#include <hip/hip_bf16.h>

using bf16 = __hip_bfloat16;

constexpr int B  = 8;
constexpr int N0 = 8192;
constexpr int NS = 2048;
constexpr int CP = 512;
constexpr int CS = 256;
constexpr int C1 = 256;
constexpr int C2 = 256;
constexpr int K1 = CP + CS;          // 768
constexpr int COLS = B * N0;         // 65536
constexpr float BN_EPS = 1e-3f;
constexpr float SLOPE  = 0.01f;

typedef short  short8 __attribute__((ext_vector_type(8)));
typedef float  f32x4  __attribute__((ext_vector_type(4)));

typedef __attribute__((address_space(1))) unsigned int gas_uint;
typedef __attribute__((address_space(3))) unsigned int las_uint;

// manual RNE fp32->bf16 (no NaNs in this workload) and back
__device__ __forceinline__ unsigned short f2bu(float f) {
  unsigned int u = __float_as_uint(f);
  return (unsigned short)((u + 0x7fffu + ((u >> 16) & 1u)) >> 16);
}
__device__ __forceinline__ float bu2f(unsigned short v) {
  return __uint_as_float((unsigned int)v << 16);
}

// ---------------- prep: fp32 weights -> bf16 (row-major [M][K]), zero stats ----------------
__global__ __launch_bounds__(256) void prep_kernel(
    const float* __restrict__ W1, const float* __restrict__ W2,
    unsigned short* __restrict__ W1b, unsigned short* __restrict__ W2b,
    float* __restrict__ stats)
{
  int id = blockIdx.x * 256 + threadIdx.x;
  if (id < 1024) stats[id] = 0.0f;
  if (id < C1 * K1) W1b[id] = f2bu(W1[id]);
  if (id < C2 * C1) W2b[id] = f2bu(W2[id]);
}

// =======================================================================
// 3-NN, slice-split: block = 64 queries x 4 slices (256 thr).
// Each thread scans 512 source points -> local top-3; stable LDS merge.
// =======================================================================
__global__ __launch_bounds__(256) void knn_kernel(
    const float* __restrict__ xyz, const float* __restrict__ xyz_prev,
    float* __restrict__ wq, int* __restrict__ iq)
{
#pragma clang fp contract(off)
  __shared__ float4 sp[NS];                 // x,y,z,|p|^2  (32 KB)
  __shared__ float  md[4][64][3];           // per-slice top-3 dists (3 KB)
  __shared__ int    mi[4][64][3];           // per-slice top-3 idx   (3 KB)
  const int b = blockIdx.y;
  const float* xp = xyz_prev + (size_t)b * 3 * NS;
  for (int j = threadIdx.x; j < NS; j += 256) {
    float x = xp[j], y = xp[NS + j], z = xp[2 * NS + j];
    sp[j] = make_float4(x, y, z, (x * x + y * y) + z * z);   // numpy association
  }
  __syncthreads();

  const int q  = threadIdx.x & 63;          // query within block (lane id)
  const int sl = threadIdx.x >> 6;          // slice = wave id
  const int n  = blockIdx.x * 64 + q;
  const float* xq = xyz + (size_t)b * 3 * N0;
  float qx = xq[n], qy = xq[N0 + n], qz = xq[2 * N0 + n];
  float qq = (qx * qx + qy * qy) + qz * qz;

  float d0 = 1e30f, d1 = 1e30f, d2 = 1e30f;
  int   i0 = 0, i1 = 0, i2 = 0;
  const int j0 = sl * (NS / 4), j1 = j0 + (NS / 4);
#pragma unroll 4
  for (int j = j0; j < j1; ++j) {
    float4 p = sp[j];
    float dot = (qx * p.x + qy * p.y) + qz * p.z;
    float d = (qq + p.w) - 2.0f * dot;      // numpy association
    if (d < d0)      { d2 = d1; i2 = i1; d1 = d0; i1 = i0; d0 = d; i0 = j; }
    else if (d < d1) { d2 = d1; i2 = i1; d1 = d;  i1 = j; }
    else if (d < d2) { d2 = d;  i2 = j; }
  }
  md[sl][q][0] = d0; md[sl][q][1] = d1; md[sl][q][2] = d2;
  mi[sl][q][0] = i0; mi[sl][q][1] = i1; mi[sl][q][2] = i2;
  __syncthreads();

  if (threadIdx.x < 64) {
    float e0 = 1e30f, e1 = 1e30f, e2 = 1e30f;
    int   k0 = 0, k1 = 0, k2 = 0;
#pragma unroll
    for (int s = 0; s < 4; ++s) {
#pragma unroll
      for (int t = 0; t < 3; ++t) {
        float d = md[s][q][t]; int ii = mi[s][q][t];
        if (d < e0)      { e2 = e1; k2 = k1; e1 = e0; k1 = k0; e0 = d; k0 = ii; }
        else if (d < e1) { e2 = e1; k2 = k1; e1 = d;  k1 = ii; }
        else if (d < e2) { e2 = d;  k2 = ii; }
      }
    }
    e0 = fmaxf(e0, 1e-10f); e1 = fmaxf(e1, 1e-10f); e2 = fmaxf(e2, 1e-10f);
    float v0 = 1.0f / (e0 + 1e-8f), v1 = 1.0f / (e1 + 1e-8f), v2 = 1.0f / (e2 + 1e-8f);
    float s = (v0 + v1) + v2;
    const int gi = (b * N0 + n) * 3;
    wq[gi + 0] = v0 / s; wq[gi + 1] = v1 / s; wq[gi + 2] = v2 / s;
    iq[gi + 0] = k0;     iq[gi + 1] = k1;     iq[gi + 2] = k2;
  }
}

// =======================================================================
// interp: LDS-gather. Block = (b, 16-channel group, n-half).
// =======================================================================
__global__ __launch_bounds__(256) void interp_kernel(
    const float* __restrict__ feat_prev, const int* __restrict__ iq,
    const float* __restrict__ wq, unsigned short* __restrict__ Xt)
{
  __shared__ unsigned short sf[16 * 2048];        // 64 KB
  const int bx = blockIdx.x;                      // 512 blocks
  const int b  = bx >> 6;                         // 8
  const int cg = (bx >> 1) & 31;                  // 32 channel groups
  const int nh = bx & 1;                          // n-half
  const int c0 = cg * 16;
  const float* fp = feat_prev + ((size_t)b * CP + c0) * NS;

  for (int id = threadIdx.x; id < 8192; id += 256) {
    float4 v = reinterpret_cast<const float4*>(fp)[id];
    ushort4 o;
    o.x = f2bu(v.x); o.y = f2bu(v.y); o.z = f2bu(v.z); o.w = f2bu(v.w);
    *reinterpret_cast<ushort4*>(&sf[id * 4]) = o;
  }
  __syncthreads();

  const int nbase = nh * 4096;
  for (int it = 0; it < 16; ++it) {
    const int n    = nbase + it * 256 + threadIdx.x;
    const int gcol = b * N0 + n;
    const int gq   = gcol * 3;
    const int i0 = iq[gq], i1 = iq[gq + 1], i2 = iq[gq + 2];
    const float w0 = wq[gq], w1 = wq[gq + 1], w2 = wq[gq + 2];
    unsigned short outv[16];
#pragma unroll
    for (int c = 0; c < 16; ++c) {
      const unsigned short* row = &sf[c * 2048];
      float v = w0 * bu2f(row[i0]) + w1 * bu2f(row[i1]) + w2 * bu2f(row[i2]);
      outv[c] = f2bu(v);
    }
    unsigned short* dst = Xt + (size_t)gcol * K1 + c0;
    *reinterpret_cast<short8*>(dst)     = *reinterpret_cast<short8*>(&outv[0]);
    *reinterpret_cast<short8*>(dst + 8) = *reinterpret_cast<short8*>(&outv[8]);
  }
}

// =======================================================================
// skipT: transpose skip fp32 [c][n] -> Xt[n][512+c] bf16. Tile 64x64.
// =======================================================================
__global__ __launch_bounds__(256) void skipt_kernel(
    const float* __restrict__ skip, unsigned short* __restrict__ Xt)
{
  __shared__ float T[64][65];
  const int kt   = blockIdx.x & 3;               // 4 k-tiles of 64
  const int ct   = blockIdx.x >> 2;              // 1024 col-tiles of 64
  const int col0 = ct * 64;
  const int b    = col0 >> 13;
  const int n0   = col0 & 8191;
  const float* src = skip + ((size_t)b * CS + kt * 64) * N0 + n0;

  for (int id = threadIdx.x; id < 1024; id += 256) {
    int r = id >> 4, q = id & 15;
    float4 v = *reinterpret_cast<const float4*>(src + (size_t)r * N0 + q * 4);
    T[r][q * 4 + 0] = v.x; T[r][q * 4 + 1] = v.y;
    T[r][q * 4 + 2] = v.z; T[r][q * 4 + 3] = v.w;
  }
  __syncthreads();
  for (int id = threadIdx.x; id < 512; id += 256) {
    int n = id >> 3, q = id & 7;
    alignas(16) unsigned short tmp[8];
#pragma unroll
    for (int j = 0; j < 8; ++j) tmp[j] = f2bu(T[q * 8 + j][n]);
    *reinterpret_cast<short8*>(Xt + (size_t)(col0 + n) * K1 + CP + kt * 64 + q * 8) =
        *reinterpret_cast<short8*>(tmp);
  }
}

// =======================================================================
// MFMA GEMM1 (m97 structure): global_load_lds width-16 staging, unpadded
// [128][64] LDS tiles, 2 barriers/K-step. Y1t[n][c1] bf16 + BN1 stats.
// grid (512, 2)
// =======================================================================
__global__ __launch_bounds__(256, 3) void gemm1_kernel(
    const unsigned short* __restrict__ W1b, const unsigned short* __restrict__ Xt,
    unsigned short* __restrict__ Y1t, float* __restrict__ stats)
{
  __shared__ unsigned short As[128 * 64];   // [m][k] linear, 16 KB
  __shared__ unsigned short Bs[128 * 64];   // [n][k] linear, 16 KB

  const int tid   = threadIdx.x;
  const int gcol0 = blockIdx.x * 128;
  const int bm    = blockIdx.y;

  const int wv = tid >> 6, lane = tid & 63;
  const int wm = (wv & 1) * 64, wn = (wv >> 1) * 64;
  const int qm = lane & 15, quad = lane >> 4;
  const int lr = lane >> 3, lc = lane & 7;   // lane -> (row-in-8, 16B-chunk)

  f32x4 acc[4][4];
#pragma unroll
  for (int i = 0; i < 4; ++i)
#pragma unroll
    for (int j = 0; j < 4; ++j) acc[i][j] = (f32x4){0.f, 0.f, 0.f, 0.f};

  const unsigned short* aBase = W1b + (size_t)(bm * 128) * K1;

  for (int kt = 0; kt < K1 / 64; ++kt) {
    const int kof = kt * 64 + lc * 8;
    // stage A (16 KB) + B (16 KB): wave wv covers 1KB chunks wv*4..wv*4+3 of each.
    // LDS dest = wave-uniform base + lane*16 (HW); global src = per-lane.
#pragma unroll
    for (int t = 0; t < 4; ++t) {
      const int ch = wv * 4 + t;             // 0..15
      const int r  = ch * 8 + lr;            // row 0..127
      __builtin_amdgcn_global_load_lds(
          (gas_uint*)(aBase + (size_t)r * K1 + kof),
          (las_uint*)(&As[ch * 512]), 16, 0, 0);
      __builtin_amdgcn_global_load_lds(
          (gas_uint*)(Xt + (size_t)(gcol0 + r) * K1 + kof),
          (las_uint*)(&Bs[ch * 512]), 16, 0, 0);
    }
    __syncthreads();                          // drains vmcnt -> tiles ready
#pragma unroll
    for (int h = 0; h < 2; ++h) {
      short8 af[4], bf[4];
#pragma unroll
      for (int i = 0; i < 4; ++i)
        af[i] = *reinterpret_cast<const short8*>(&As[(wm + i * 16 + qm) * 64 + h * 32 + quad * 8]);
#pragma unroll
      for (int j = 0; j < 4; ++j)
        bf[j] = *reinterpret_cast<const short8*>(&Bs[(wn + j * 16 + qm) * 64 + h * 32 + quad * 8]);
#pragma unroll
      for (int i = 0; i < 4; ++i)
#pragma unroll
        for (int j = 0; j < 4; ++j)
          acc[i][j] = __builtin_amdgcn_mfma_f32_16x16x32_bf16(af[i], bf[j], acc[i][j], 0, 0, 0);
    }
    __syncthreads();                          // compute done before restage
  }

  // epilogue: Y1t[n][c] bf16 (8 B contiguous) + BN1 stats
#pragma unroll
  for (int i = 0; i < 4; ++i) {
    const int mb = bm * 128 + wm + i * 16 + quad * 4;
    float s[4] = {0.f, 0.f, 0.f, 0.f}, s2[4] = {0.f, 0.f, 0.f, 0.f};
#pragma unroll
    for (int j = 0; j < 4; ++j) {
      const int gc = gcol0 + wn + j * 16 + qm;
      ushort4 o;
      o.x = f2bu(acc[i][j][0]); o.y = f2bu(acc[i][j][1]);
      o.z = f2bu(acc[i][j][2]); o.w = f2bu(acc[i][j][3]);
      *reinterpret_cast<ushort4*>(Y1t + (size_t)gc * C1 + mb) = o;
#pragma unroll
      for (int r = 0; r < 4; ++r) {
        float v = acc[i][j][r];
        s[r] += v; s2[r] += v * v;
      }
    }
#pragma unroll
    for (int m = 1; m < 16; m <<= 1) {
#pragma unroll
      for (int r = 0; r < 4; ++r) { s[r] += __shfl_xor(s[r], m); s2[r] += __shfl_xor(s2[r], m); }
    }
    if (qm == 0) {
#pragma unroll
      for (int r = 0; r < 4; ++r) {
        atomicAdd(&stats[mb + r], s[r]);
        atomicAdd(&stats[C1 + mb + r], s2[r]);
      }
    }
  }
}

// ---------------- affine: fold BN stats + gamma/beta into scale/shift ----------------
__global__ __launch_bounds__(256) void affine_kernel(
    const float* __restrict__ s, const float* __restrict__ g,
    const float* __restrict__ bb, float* __restrict__ a)
{
  int c = threadIdx.x;
  float inv = 1.0f / (float)COLS;
  float mean = s[c] * inv;
  float var  = s[C1 + c] * inv - mean * mean;
  float sc   = g[c] / sqrtf(var + BN_EPS);
  a[c]      = sc;
  a[C1 + c] = bb[c] - mean * sc;
}

// =======================================================================
// bn1 apply: in-place BN1 + LeakyReLU on Y1t (bf16 -> bf16), 8 ch/thread.
// Numerics identical to the old gemm2 fused staging path.
// =======================================================================
__global__ __launch_bounds__(256) void bn1_apply_kernel(
    unsigned short* __restrict__ Y1t, const float* __restrict__ aff)
{
  const size_t id = (size_t)blockIdx.x * 256 + threadIdx.x;  // short8 granule
  const int c0 = ((int)id & 31) * 8;                         // (id*8) % 256
  short8 v = reinterpret_cast<const short8*>(Y1t)[id];
  float4 sc0 = *reinterpret_cast<const float4*>(aff + c0);
  float4 sc1 = *reinterpret_cast<const float4*>(aff + c0 + 4);
  float4 sh0 = *reinterpret_cast<const float4*>(aff + C1 + c0);
  float4 sh1 = *reinterpret_cast<const float4*>(aff + C1 + c0 + 4);
  alignas(16) unsigned short o[8];
#pragma unroll
  for (int j = 0; j < 4; ++j) {
    float f = bu2f((unsigned short)v[j]) * (&sc0.x)[j] + (&sh0.x)[j];
    f = (f >= 0.f) ? f : SLOPE * f;
    o[j] = f2bu(f);
  }
#pragma unroll
  for (int j = 0; j < 4; ++j) {
    float f = bu2f((unsigned short)v[4 + j]) * (&sc1.x)[j] + (&sh1.x)[j];
    f = (f >= 0.f) ? f : SLOPE * f;
    o[4 + j] = f2bu(f);
  }
  reinterpret_cast<short8*>(Y1t)[id] = *reinterpret_cast<short8*>(o);
}

// =======================================================================
// MFMA GEMM2 (m97 structure, clean stream): W2 * Y1bn. fp32 out + BN2 stats.
// grid (512, 2)
// =======================================================================
__global__ __launch_bounds__(256, 3) void gemm2_kernel(
    const unsigned short* __restrict__ W2b, const unsigned short* __restrict__ Y1t,
    float* __restrict__ out_nf, float* __restrict__ stats2)
{
  __shared__ unsigned short As[128 * 64];
  __shared__ unsigned short Bs[128 * 64];

  const int tid   = threadIdx.x;
  const int gcol0 = blockIdx.x * 128;
  const int bm    = blockIdx.y;
  const int b     = gcol0 >> 13;
  const int ncol0 = gcol0 & 8191;

  const int wv = tid >> 6, lane = tid & 63;
  const int wm = (wv & 1) * 64, wn = (wv >> 1) * 64;
  const int qm = lane & 15, quad = lane >> 4;
  const int lr = lane >> 3, lc = lane & 7;

  f32x4 acc[4][4];
#pragma unroll
  for (int i = 0; i < 4; ++i)
#pragma unroll
    for (int j = 0; j < 4; ++j) acc[i][j] = (f32x4){0.f, 0.f, 0.f, 0.f};

  const unsigned short* aBase = W2b + (size_t)(bm * 128) * C1;

  for (int kt = 0; kt < C1 / 64; ++kt) {
    const int kof = kt * 64 + lc * 8;
#pragma unroll
    for (int t = 0; t < 4; ++t) {
      const int ch = wv * 4 + t;
      const int r  = ch * 8 + lr;
      __builtin_amdgcn_global_load_lds(
          (gas_uint*)(aBase + (size_t)r * C1 + kof),
          (las_uint*)(&As[ch * 512]), 16, 0, 0);
      __builtin_amdgcn_global_load_lds(
          (gas_uint*)(Y1t + (size_t)(gcol0 + r) * C1 + kof),
          (las_uint*)(&Bs[ch * 512]), 16, 0, 0);
    }
    __syncthreads();
#pragma unroll
    for (int h = 0; h < 2; ++h) {
      short8 af[4], bf[4];
#pragma unroll
      for (int i = 0; i < 4; ++i)
        af[i] = *reinterpret_cast<const short8*>(&As[(wm + i * 16 + qm) * 64 + h * 32 + quad * 8]);
#pragma unroll
      for (int j = 0; j < 4; ++j)
        bf[j] = *reinterpret_cast<const short8*>(&Bs[(wn + j * 16 + qm) * 64 + h * 32 + quad * 8]);
#pragma unroll
      for (int i = 0; i < 4; ++i)
#pragma unroll
        for (int j = 0; j < 4; ++j)
          acc[i][j] = __builtin_amdgcn_mfma_f32_16x16x32_bf16(af[i], bf[j], acc[i][j], 0, 0, 0);
    }
    __syncthreads();
  }

  // epilogue: raw fp32 Y2 to out_nf [b][m][N0] + BN2 stats
#pragma unroll
  for (int i = 0; i < 4; ++i) {
    const int mb = bm * 128 + wm + i * 16 + quad * 4;
    float s[4] = {0.f, 0.f, 0.f, 0.f}, s2[4] = {0.f, 0.f, 0.f, 0.f};
#pragma unroll
    for (int j = 0; j < 4; ++j) {
      const int col = ncol0 + wn + j * 16 + qm;
#pragma unroll
      for (int r = 0; r < 4; ++r) {
        float v = acc[i][j][r];
        out_nf[((size_t)b * C2 + mb + r) * N0 + col] = v;
        s[r] += v; s2[r] += v * v;
      }
    }
#pragma unroll
    for (int m = 1; m < 16; m <<= 1) {
#pragma unroll
      for (int r = 0; r < 4; ++r) { s[r] += __shfl_xor(s[r], m); s2[r] += __shfl_xor(s2[r], m); }
    }
    if (qm == 0) {
#pragma unroll
      for (int r = 0; r < 4; ++r) {
        atomicAdd(&stats2[mb + r], s[r]);
        atomicAdd(&stats2[C2 + mb + r], s2[r]);
      }
    }
  }
}

// ---------------- finalize: in-place BN2 + LeakyReLU on out_nf (fp32) ----------------
__global__ __launch_bounds__(256) void finalize_kernel(float* __restrict__ nf,
                                                       const float* __restrict__ aff)
{
  int id4 = blockIdx.x * 256 + threadIdx.x;      // float4-granule index
  int e = id4 * 4;
  int c = (e % (C2 * N0)) / N0;
  float sc = aff[c], sh = aff[C1 + c];
  float4 v = reinterpret_cast<float4*>(nf)[id4];
  v.x = v.x * sc + sh; v.x = (v.x >= 0.f) ? v.x : SLOPE * v.x;
  v.y = v.y * sc + sh; v.y = (v.y >= 0.f) ? v.y : SLOPE * v.y;
  v.z = v.z * sc + sh; v.z = (v.z >= 0.f) ? v.z : SLOPE * v.z;
  v.w = v.w * sc + sh; v.w = (v.w >= 0.f) ? v.w : SLOPE * v.w;
  reinterpret_cast<float4*>(nf)[id4] = v;
}

// ---------------- copy xyz passthrough (fp32) ----------------
__global__ __launch_bounds__(256) void copy_xyz_kernel(const float* __restrict__ xyz,
                                                       float* __restrict__ out)
{
  int id = blockIdx.x * 256 + threadIdx.x;       // float4 granules, 12288 total
  reinterpret_cast<float4*>(out)[id] = reinterpret_cast<const float4*>(xyz)[id];
}

extern "C" void kernel_launch(void* const* d_in, const int* in_sizes, int n_in,
                              void* d_out, int out_size, void* d_ws, size_t ws_size,
                              hipStream_t stream)
{
  const float* xyz       = (const float*)d_in[0];
  const float* skip      = (const float*)d_in[1];
  const float* xyz_prev  = (const float*)d_in[2];
  const float* feat_prev = (const float*)d_in[3];
  const float* W1        = (const float*)d_in[4];
  const float* g1        = (const float*)d_in[5];
  const float* b1        = (const float*)d_in[6];
  const float* W2        = (const float*)d_in[7];
  const float* g2        = (const float*)d_in[8];
  const float* b2        = (const float*)d_in[9];

  float* out    = (float*)d_out;
  float* out_nf = out + (size_t)B * 3 * N0;      // [B][C2][N0] fp32

  char* ws = (char*)d_ws;
  float*          wq    = (float*)(ws + 0);                 //   786432 B
  int*            iq    = (int*)  (ws + 786432);            //   786432 B
  unsigned short* W1b   = (unsigned short*)(ws + 1572864);  //   393216 B
  unsigned short* W2b   = (unsigned short*)(ws + 1966080);  //   131072 B
  float*          stats = (float*)(ws + 2097152);           //     4096 B
  float*          aff   = (float*)(ws + 2101248);           //     4096 B
  unsigned short* Y1t   = (unsigned short*)(ws + 2105344);  // 33554432 B  [COLS][C1]
  unsigned short* Xt    = (unsigned short*)(ws + 35659776); // 100663296 B [COLS][K1]
  // total: 136,323,072 B

  prep_kernel<<<768, 256, 0, stream>>>(W1, W2, W1b, W2b, stats);
  knn_kernel<<<dim3(N0 / 64, B), 256, 0, stream>>>(xyz, xyz_prev, wq, iq);
  interp_kernel<<<512, 256, 0, stream>>>(feat_prev, iq, wq, Xt);
  skipt_kernel<<<4096, 256, 0, stream>>>(skip, Xt);
  gemm1_kernel<<<dim3(512, 2), 256, 0, stream>>>(W1b, Xt, Y1t, stats);
  affine_kernel<<<1, 256, 0, stream>>>(stats, g1, b1, aff);
  bn1_apply_kernel<<<(COLS * C1) / (8 * 256), 256, 0, stream>>>(Y1t, aff);
  gemm2_kernel<<<dim3(512, 2), 256, 0, stream>>>(W2b, Y1t, out_nf, stats + 512);
  affine_kernel<<<1, 256, 0, stream>>>(stats + 512, g2, b2, aff + 512);
  finalize_kernel<<<(C2 * N0 * B) / (4 * 256), 256, 0, stream>>>(out_nf, aff + 512);
  copy_xyz_kernel<<<(B * 3 * N0) / (4 * 256), 256, 0, stream>>>(xyz, out);
}

// Round 2
// 572.029 us; speedup vs baseline: 1.2981x; 1.1598x over previous
//
#include <hip/hip_runtime.h>
#include <hip/hip_bf16.h>

using bf16 = __hip_bfloat16;

constexpr int B  = 8;
constexpr int N0 = 8192;
constexpr int NS = 2048;
constexpr int CP = 512;
constexpr int CS = 256;
constexpr int C1 = 256;
constexpr int C2 = 256;
constexpr int K1 = CP + CS;          // 768
constexpr int COLS = B * N0;         // 65536
constexpr float BN_EPS = 1e-3f;
constexpr float SLOPE  = 0.01f;

typedef short  short8 __attribute__((ext_vector_type(8)));
typedef float  f32x4  __attribute__((ext_vector_type(4)));

typedef __attribute__((address_space(1))) unsigned int gas_uint;
typedef __attribute__((address_space(3))) unsigned int las_uint;

// manual RNE fp32->bf16 (no NaNs in this workload) and back
__device__ __forceinline__ unsigned short f2bu(float f) {
  unsigned int u = __float_as_uint(f);
  return (unsigned short)((u + 0x7fffu + ((u >> 16) & 1u)) >> 16);
}
__device__ __forceinline__ float bu2f(unsigned short v) {
  return __uint_as_float((unsigned int)v << 16);
}

// ---------------- prep: fp32 weights -> bf16 (row-major [M][K]), zero stats ----------------
__global__ __launch_bounds__(256) void prep_kernel(
    const float* __restrict__ W1, const float* __restrict__ W2,
    unsigned short* __restrict__ W1b, unsigned short* __restrict__ W2b,
    float* __restrict__ stats)
{
  int id = blockIdx.x * 256 + threadIdx.x;
  if (id < 1024) stats[id] = 0.0f;
  if (id < C1 * K1) W1b[id] = f2bu(W1[id]);
  if (id < C2 * C1) W2b[id] = f2bu(W2[id]);
}

// =======================================================================
// 3-NN, slice-split: block = 64 queries x 4 slices (256 thr).
// =======================================================================
__global__ __launch_bounds__(256) void knn_kernel(
    const float* __restrict__ xyz, const float* __restrict__ xyz_prev,
    float* __restrict__ wq, int* __restrict__ iq)
{
#pragma clang fp contract(off)
  __shared__ float4 sp[NS];                 // x,y,z,|p|^2  (32 KB)
  __shared__ float  md[4][64][3];
  __shared__ int    mi[4][64][3];
  const int b = blockIdx.y;
  const float* xp = xyz_prev + (size_t)b * 3 * NS;
  for (int j = threadIdx.x; j < NS; j += 256) {
    float x = xp[j], y = xp[NS + j], z = xp[2 * NS + j];
    sp[j] = make_float4(x, y, z, (x * x + y * y) + z * z);   // numpy association
  }
  __syncthreads();

  const int q  = threadIdx.x & 63;
  const int sl = threadIdx.x >> 6;
  const int n  = blockIdx.x * 64 + q;
  const float* xq = xyz + (size_t)b * 3 * N0;
  float qx = xq[n], qy = xq[N0 + n], qz = xq[2 * N0 + n];
  float qq = (qx * qx + qy * qy) + qz * qz;

  float d0 = 1e30f, d1 = 1e30f, d2 = 1e30f;
  int   i0 = 0, i1 = 0, i2 = 0;
  const int j0 = sl * (NS / 4), j1 = j0 + (NS / 4);
#pragma unroll 4
  for (int j = j0; j < j1; ++j) {
    float4 p = sp[j];
    float dot = (qx * p.x + qy * p.y) + qz * p.z;
    float d = (qq + p.w) - 2.0f * dot;      // numpy association
    if (d < d0)      { d2 = d1; i2 = i1; d1 = d0; i1 = i0; d0 = d; i0 = j; }
    else if (d < d1) { d2 = d1; i2 = i1; d1 = d;  i1 = j; }
    else if (d < d2) { d2 = d;  i2 = j; }
  }
  md[sl][q][0] = d0; md[sl][q][1] = d1; md[sl][q][2] = d2;
  mi[sl][q][0] = i0; mi[sl][q][1] = i1; mi[sl][q][2] = i2;
  __syncthreads();

  if (threadIdx.x < 64) {
    float e0 = 1e30f, e1 = 1e30f, e2 = 1e30f;
    int   k0 = 0, k1 = 0, k2 = 0;
#pragma unroll
    for (int s = 0; s < 4; ++s) {
#pragma unroll
      for (int t = 0; t < 3; ++t) {
        float d = md[s][q][t]; int ii = mi[s][q][t];
        if (d < e0)      { e2 = e1; k2 = k1; e1 = e0; k1 = k0; e0 = d; k0 = ii; }
        else if (d < e1) { e2 = e1; k2 = k1; e1 = d;  k1 = ii; }
        else if (d < e2) { e2 = d;  k2 = ii; }
      }
    }
    e0 = fmaxf(e0, 1e-10f); e1 = fmaxf(e1, 1e-10f); e2 = fmaxf(e2, 1e-10f);
    float v0 = 1.0f / (e0 + 1e-8f), v1 = 1.0f / (e1 + 1e-8f), v2 = 1.0f / (e2 + 1e-8f);
    float s = (v0 + v1) + v2;
    const int gi = (b * N0 + n) * 3;
    wq[gi + 0] = v0 / s; wq[gi + 1] = v1 / s; wq[gi + 2] = v2 / s;
    iq[gi + 0] = k0;     iq[gi + 1] = k1;     iq[gi + 2] = k2;
  }
}

// =======================================================================
// interp: LDS-gather. Block = (b, 16-channel group, n-half).
// =======================================================================
__global__ __launch_bounds__(256) void interp_kernel(
    const float* __restrict__ feat_prev, const int* __restrict__ iq,
    const float* __restrict__ wq, unsigned short* __restrict__ Xt)
{
  __shared__ unsigned short sf[16 * 2048];        // 64 KB
  const int bx = blockIdx.x;                      // 512 blocks
  const int b  = bx >> 6;
  const int cg = (bx >> 1) & 31;
  const int nh = bx & 1;
  const int c0 = cg * 16;
  const float* fp = feat_prev + ((size_t)b * CP + c0) * NS;

  for (int id = threadIdx.x; id < 8192; id += 256) {
    float4 v = reinterpret_cast<const float4*>(fp)[id];
    ushort4 o;
    o.x = f2bu(v.x); o.y = f2bu(v.y); o.z = f2bu(v.z); o.w = f2bu(v.w);
    *reinterpret_cast<ushort4*>(&sf[id * 4]) = o;
  }
  __syncthreads();

  const int nbase = nh * 4096;
  for (int it = 0; it < 16; ++it) {
    const int n    = nbase + it * 256 + threadIdx.x;
    const int gcol = b * N0 + n;
    const int gq   = gcol * 3;
    const int i0 = iq[gq], i1 = iq[gq + 1], i2 = iq[gq + 2];
    const float w0 = wq[gq], w1 = wq[gq + 1], w2 = wq[gq + 2];
    unsigned short outv[16];
#pragma unroll
    for (int c = 0; c < 16; ++c) {
      const unsigned short* row = &sf[c * 2048];
      float v = w0 * bu2f(row[i0]) + w1 * bu2f(row[i1]) + w2 * bu2f(row[i2]);
      outv[c] = f2bu(v);
    }
    unsigned short* dst = Xt + (size_t)gcol * K1 + c0;
    *reinterpret_cast<short8*>(dst)     = *reinterpret_cast<short8*>(&outv[0]);
    *reinterpret_cast<short8*>(dst + 8) = *reinterpret_cast<short8*>(&outv[8]);
  }
}

// =======================================================================
// skipT: transpose skip fp32 [c][n] -> Xt[n][512+c] bf16. Tile 64x64.
// =======================================================================
__global__ __launch_bounds__(256) void skipt_kernel(
    const float* __restrict__ skip, unsigned short* __restrict__ Xt)
{
  __shared__ float T[64][65];
  const int kt   = blockIdx.x & 3;
  const int ct   = blockIdx.x >> 2;
  const int col0 = ct * 64;
  const int b    = col0 >> 13;
  const int n0   = col0 & 8191;
  const float* src = skip + ((size_t)b * CS + kt * 64) * N0 + n0;

  for (int id = threadIdx.x; id < 1024; id += 256) {
    int r = id >> 4, q = id & 15;
    float4 v = *reinterpret_cast<const float4*>(src + (size_t)r * N0 + q * 4);
    T[r][q * 4 + 0] = v.x; T[r][q * 4 + 1] = v.y;
    T[r][q * 4 + 2] = v.z; T[r][q * 4 + 3] = v.w;
  }
  __syncthreads();
  for (int id = threadIdx.x; id < 512; id += 256) {
    int n = id >> 3, q = id & 7;
    alignas(16) unsigned short tmp[8];
#pragma unroll
    for (int j = 0; j < 8; ++j) tmp[j] = f2bu(T[q * 8 + j][n]);
    *reinterpret_cast<short8*>(Xt + (size_t)(col0 + n) * K1 + CP + kt * 64 + q * 8) =
        *reinterpret_cast<short8*>(tmp);
  }
}

// =======================================================================
// MFMA GEMM1, v2: BM=256 (full M) x BN=64, BK=64, 4 waves.
// Double-buffered LDS + prefetch (T3 minimum-2-phase): stage k+1 via
// global_load_lds BEFORE computing k; ONE vmcnt-drain barrier per K-step.
// 16B-chunk XOR swizzle: linear LDS dest, inverse-swz SOURCE, swz READ.
// Xt read exactly once (grid = 1024 col-tiles).  LDS 80 KB -> 2 blk/CU.
// =======================================================================
__global__ __launch_bounds__(256) void gemm1_kernel(
    const unsigned short* __restrict__ W1b, const unsigned short* __restrict__ Xt,
    unsigned short* __restrict__ Y1t, float* __restrict__ stats)
{
  __shared__ unsigned short As[2 * 256 * 64];   // 2 x 32 KB  [buf][m][k]
  __shared__ unsigned short Bs[2 * 64 * 64];    // 2 x  8 KB  [buf][n][k]

  const int tid   = threadIdx.x;
  const int gcol0 = blockIdx.x * 64;

  const int wv = tid >> 6, lane = tid & 63;
  const int wm = wv * 64;                  // wave's 64 M-rows
  const int qm = lane & 15, quad = lane >> 4;
  const int lr = lane >> 3, lc = lane & 7; // stage: (row-in-8, 16B-chunk)
  const int sw_src = (lc ^ lr) * 8;        // inverse-swizzled source k-offset
  const int sw_rd  = qm & 7;               // read-side row XOR key

  f32x4 acc[4][4];
#pragma unroll
  for (int i = 0; i < 4; ++i)
#pragma unroll
    for (int j = 0; j < 4; ++j) acc[i][j] = (f32x4){0.f, 0.f, 0.f, 0.f};

  // stage one K-tile (A: 256x64 = 32 chunks/wave-instr groups, B: 64x64)
  auto stage = [&](int kt, int buf) {
    const int kofA = kt * 64 + sw_src;
#pragma unroll
    for (int t = 0; t < 8; ++t) {
      const int ch = wv * 8 + t;           // 0..31 (64-chunk groups)
      const int r  = ch * 8 + lr;          // m-row 0..255, r&7 == lr
      __builtin_amdgcn_global_load_lds(
          (const gas_uint*)(W1b + (size_t)r * K1 + kofA),
          (las_uint*)(&As[buf * (256 * 64) + ch * 512]), 16, 0, 0);
    }
#pragma unroll
    for (int t = 0; t < 2; ++t) {
      const int ch = wv * 2 + t;           // 0..7
      const int r  = ch * 8 + lr;          // n-row 0..63, r&7 == lr
      __builtin_amdgcn_global_load_lds(
          (const gas_uint*)(Xt + (size_t)(gcol0 + r) * K1 + kofA),
          (las_uint*)(&Bs[buf * (64 * 64) + ch * 512]), 16, 0, 0);
    }
  };

  stage(0, 0);
  __syncthreads();                          // drain vmcnt: buf0 ready

  for (int kt = 0; kt < K1 / 64; ++kt) {
    const int cur = kt & 1;
    if (kt + 1 < K1 / 64) stage(kt + 1, cur ^ 1);   // loads fly during compute
    const unsigned short* Ab = &As[cur * (256 * 64)];
    const unsigned short* Bb = &Bs[cur * (64 * 64)];
#pragma unroll
    for (int h = 0; h < 2; ++h) {
      short8 af[4], bf[4];
#pragma unroll
      for (int i = 0; i < 4; ++i)
        af[i] = *reinterpret_cast<const short8*>(
            &Ab[(wm + i * 16 + qm) * 64 + ((h * 4 + quad) ^ sw_rd) * 8]);
#pragma unroll
      for (int j = 0; j < 4; ++j)
        bf[j] = *reinterpret_cast<const short8*>(
            &Bb[(j * 16 + qm) * 64 + ((h * 4 + quad) ^ sw_rd) * 8]);
#pragma unroll
      for (int i = 0; i < 4; ++i)
#pragma unroll
        for (int j = 0; j < 4; ++j)
          acc[i][j] = __builtin_amdgcn_mfma_f32_16x16x32_bf16(af[i], bf[j], acc[i][j], 0, 0, 0);
    }
    __syncthreads();   // next buf staged + everyone done reading cur
  }

  // epilogue: Y1t[n][c] bf16 (8 B contiguous) + BN1 stats
#pragma unroll
  for (int i = 0; i < 4; ++i) {
    const int mb = wm + i * 16 + quad * 4;
    float s[4] = {0.f, 0.f, 0.f, 0.f}, s2[4] = {0.f, 0.f, 0.f, 0.f};
#pragma unroll
    for (int j = 0; j < 4; ++j) {
      const int gc = gcol0 + j * 16 + qm;
      ushort4 o;
      o.x = f2bu(acc[i][j][0]); o.y = f2bu(acc[i][j][1]);
      o.z = f2bu(acc[i][j][2]); o.w = f2bu(acc[i][j][3]);
      *reinterpret_cast<ushort4*>(Y1t + (size_t)gc * C1 + mb) = o;
#pragma unroll
      for (int r = 0; r < 4; ++r) {
        float v = acc[i][j][r];
        s[r] += v; s2[r] += v * v;
      }
    }
#pragma unroll
    for (int m = 1; m < 16; m <<= 1) {
#pragma unroll
      for (int r = 0; r < 4; ++r) { s[r] += __shfl_xor(s[r], m); s2[r] += __shfl_xor(s2[r], m); }
    }
    if (qm == 0) {
#pragma unroll
      for (int r = 0; r < 4; ++r) {
        atomicAdd(&stats[mb + r], s[r]);
        atomicAdd(&stats[C1 + mb + r], s2[r]);
      }
    }
  }
}

// ---------------- affine: fold BN stats + gamma/beta into scale/shift ----------------
__global__ __launch_bounds__(256) void affine_kernel(
    const float* __restrict__ s, const float* __restrict__ g,
    const float* __restrict__ bb, float* __restrict__ a)
{
  int c = threadIdx.x;
  float inv = 1.0f / (float)COLS;
  float mean = s[c] * inv;
  float var  = s[C1 + c] * inv - mean * mean;
  float sc   = g[c] / sqrtf(var + BN_EPS);
  a[c]      = sc;
  a[C1 + c] = bb[c] - mean * sc;
}

// =======================================================================
// bn1 apply: in-place BN1 + LeakyReLU on Y1t (bf16 -> bf16), 8 ch/thread.
// =======================================================================
__global__ __launch_bounds__(256) void bn1_apply_kernel(
    unsigned short* __restrict__ Y1t, const float* __restrict__ aff)
{
  const size_t id = (size_t)blockIdx.x * 256 + threadIdx.x;  // short8 granule
  const int c0 = ((int)id & 31) * 8;                         // (id*8) % 256
  short8 v = reinterpret_cast<const short8*>(Y1t)[id];
  float4 sc0 = *reinterpret_cast<const float4*>(aff + c0);
  float4 sc1 = *reinterpret_cast<const float4*>(aff + c0 + 4);
  float4 sh0 = *reinterpret_cast<const float4*>(aff + C1 + c0);
  float4 sh1 = *reinterpret_cast<const float4*>(aff + C1 + c0 + 4);
  alignas(16) unsigned short o[8];
#pragma unroll
  for (int j = 0; j < 4; ++j) {
    float f = bu2f((unsigned short)v[j]) * (&sc0.x)[j] + (&sh0.x)[j];
    f = (f >= 0.f) ? f : SLOPE * f;
    o[j] = f2bu(f);
  }
#pragma unroll
  for (int j = 0; j < 4; ++j) {
    float f = bu2f((unsigned short)v[4 + j]) * (&sc1.x)[j] + (&sh1.x)[j];
    f = (f >= 0.f) ? f : SLOPE * f;
    o[4 + j] = f2bu(f);
  }
  reinterpret_cast<short8*>(Y1t)[id] = *reinterpret_cast<short8*>(o);
}

// =======================================================================
// MFMA GEMM2, v2: same BM=256 x BN=64 dbuf-prefetch structure, K=256.
// Y1t read exactly once. fp32 out + BN2 stats.
// =======================================================================
__global__ __launch_bounds__(256) void gemm2_kernel(
    const unsigned short* __restrict__ W2b, const unsigned short* __restrict__ Y1t,
    float* __restrict__ out_nf, float* __restrict__ stats2)
{
  __shared__ unsigned short As[2 * 256 * 64];   // 2 x 32 KB
  __shared__ unsigned short Bs[2 * 64 * 64];    // 2 x  8 KB

  const int tid   = threadIdx.x;
  const int gcol0 = blockIdx.x * 64;
  const int b     = gcol0 >> 13;
  const int ncol0 = gcol0 & 8191;

  const int wv = tid >> 6, lane = tid & 63;
  const int wm = wv * 64;
  const int qm = lane & 15, quad = lane >> 4;
  const int lr = lane >> 3, lc = lane & 7;
  const int sw_src = (lc ^ lr) * 8;
  const int sw_rd  = qm & 7;

  f32x4 acc[4][4];
#pragma unroll
  for (int i = 0; i < 4; ++i)
#pragma unroll
    for (int j = 0; j < 4; ++j) acc[i][j] = (f32x4){0.f, 0.f, 0.f, 0.f};

  auto stage = [&](int kt, int buf) {
    const int kofA = kt * 64 + sw_src;
#pragma unroll
    for (int t = 0; t < 8; ++t) {
      const int ch = wv * 8 + t;
      const int r  = ch * 8 + lr;
      __builtin_amdgcn_global_load_lds(
          (const gas_uint*)(W2b + (size_t)r * C1 + kofA),
          (las_uint*)(&As[buf * (256 * 64) + ch * 512]), 16, 0, 0);
    }
#pragma unroll
    for (int t = 0; t < 2; ++t) {
      const int ch = wv * 2 + t;
      const int r  = ch * 8 + lr;
      __builtin_amdgcn_global_load_lds(
          (const gas_uint*)(Y1t + (size_t)(gcol0 + r) * C1 + kofA),
          (las_uint*)(&Bs[buf * (64 * 64) + ch * 512]), 16, 0, 0);
    }
  };

  stage(0, 0);
  __syncthreads();

  for (int kt = 0; kt < C1 / 64; ++kt) {
    const int cur = kt & 1;
    if (kt + 1 < C1 / 64) stage(kt + 1, cur ^ 1);
    const unsigned short* Ab = &As[cur * (256 * 64)];
    const unsigned short* Bb = &Bs[cur * (64 * 64)];
#pragma unroll
    for (int h = 0; h < 2; ++h) {
      short8 af[4], bf[4];
#pragma unroll
      for (int i = 0; i < 4; ++i)
        af[i] = *reinterpret_cast<const short8*>(
            &Ab[(wm + i * 16 + qm) * 64 + ((h * 4 + quad) ^ sw_rd) * 8]);
#pragma unroll
      for (int j = 0; j < 4; ++j)
        bf[j] = *reinterpret_cast<const short8*>(
            &Bb[(j * 16 + qm) * 64 + ((h * 4 + quad) ^ sw_rd) * 8]);
#pragma unroll
      for (int i = 0; i < 4; ++i)
#pragma unroll
        for (int j = 0; j < 4; ++j)
          acc[i][j] = __builtin_amdgcn_mfma_f32_16x16x32_bf16(af[i], bf[j], acc[i][j], 0, 0, 0);
    }
    __syncthreads();
  }

  // epilogue: raw fp32 Y2 to out_nf [b][m][N0] + BN2 stats
#pragma unroll
  for (int i = 0; i < 4; ++i) {
    const int mb = wm + i * 16 + quad * 4;
    float s[4] = {0.f, 0.f, 0.f, 0.f}, s2[4] = {0.f, 0.f, 0.f, 0.f};
#pragma unroll
    for (int j = 0; j < 4; ++j) {
      const int col = ncol0 + j * 16 + qm;
#pragma unroll
      for (int r = 0; r < 4; ++r) {
        float v = acc[i][j][r];
        out_nf[((size_t)b * C2 + mb + r) * N0 + col] = v;
        s[r] += v; s2[r] += v * v;
      }
    }
#pragma unroll
    for (int m = 1; m < 16; m <<= 1) {
#pragma unroll
      for (int r = 0; r < 4; ++r) { s[r] += __shfl_xor(s[r], m); s2[r] += __shfl_xor(s2[r], m); }
    }
    if (qm == 0) {
#pragma unroll
      for (int r = 0; r < 4; ++r) {
        atomicAdd(&stats2[mb + r], s[r]);
        atomicAdd(&stats2[C2 + mb + r], s2[r]);
      }
    }
  }
}

// ---------------- finalize: in-place BN2 + LeakyReLU on out_nf (fp32) ----------------
__global__ __launch_bounds__(256) void finalize_kernel(float* __restrict__ nf,
                                                       const float* __restrict__ aff)
{
  int id4 = blockIdx.x * 256 + threadIdx.x;      // float4-granule index
  int e = id4 * 4;
  int c = (e % (C2 * N0)) / N0;
  float sc = aff[c], sh = aff[C1 + c];
  float4 v = reinterpret_cast<float4*>(nf)[id4];
  v.x = v.x * sc + sh; v.x = (v.x >= 0.f) ? v.x : SLOPE * v.x;
  v.y = v.y * sc + sh; v.y = (v.y >= 0.f) ? v.y : SLOPE * v.y;
  v.z = v.z * sc + sh; v.z = (v.z >= 0.f) ? v.z : SLOPE * v.z;
  v.w = v.w * sc + sh; v.w = (v.w >= 0.f) ? v.w : SLOPE * v.w;
  reinterpret_cast<float4*>(nf)[id4] = v;
}

// ---------------- copy xyz passthrough (fp32) ----------------
__global__ __launch_bounds__(256) void copy_xyz_kernel(const float* __restrict__ xyz,
                                                       float* __restrict__ out)
{
  int id = blockIdx.x * 256 + threadIdx.x;       // float4 granules, 12288 total
  reinterpret_cast<float4*>(out)[id] = reinterpret_cast<const float4*>(xyz)[id];
}

extern "C" void kernel_launch(void* const* d_in, const int* in_sizes, int n_in,
                              void* d_out, int out_size, void* d_ws, size_t ws_size,
                              hipStream_t stream)
{
  const float* xyz       = (const float*)d_in[0];
  const float* skip      = (const float*)d_in[1];
  const float* xyz_prev  = (const float*)d_in[2];
  const float* feat_prev = (const float*)d_in[3];
  const float* W1        = (const float*)d_in[4];
  const float* g1        = (const float*)d_in[5];
  const float* b1        = (const float*)d_in[6];
  const float* W2        = (const float*)d_in[7];
  const float* g2        = (const float*)d_in[8];
  const float* b2        = (const float*)d_in[9];

  float* out    = (float*)d_out;
  float* out_nf = out + (size_t)B * 3 * N0;      // [B][C2][N0] fp32

  char* ws = (char*)d_ws;
  float*          wq    = (float*)(ws + 0);                 //   786432 B
  int*            iq    = (int*)  (ws + 786432);            //   786432 B
  unsigned short* W1b   = (unsigned short*)(ws + 1572864);  //   393216 B
  unsigned short* W2b   = (unsigned short*)(ws + 1966080);  //   131072 B
  float*          stats = (float*)(ws + 2097152);           //     4096 B
  float*          aff   = (float*)(ws + 2101248);           //     4096 B
  unsigned short* Y1t   = (unsigned short*)(ws + 2105344);  // 33554432 B  [COLS][C1]
  unsigned short* Xt    = (unsigned short*)(ws + 35659776); // 100663296 B [COLS][K1]
  // total: 136,323,072 B

  prep_kernel<<<768, 256, 0, stream>>>(W1, W2, W1b, W2b, stats);
  knn_kernel<<<dim3(N0 / 64, B), 256, 0, stream>>>(xyz, xyz_prev, wq, iq);
  interp_kernel<<<512, 256, 0, stream>>>(feat_prev, iq, wq, Xt);
  skipt_kernel<<<4096, 256, 0, stream>>>(skip, Xt);
  gemm1_kernel<<<COLS / 64, 256, 0, stream>>>(W1b, Xt, Y1t, stats);
  affine_kernel<<<1, 256, 0, stream>>>(stats, g1, b1, aff);
  bn1_apply_kernel<<<(COLS * C1) / (8 * 256), 256, 0, stream>>>(Y1t, aff);
  gemm2_kernel<<<COLS / 64, 256, 0, stream>>>(W2b, Y1t, out_nf, stats + 512);
  affine_kernel<<<1, 256, 0, stream>>>(stats + 512, g2, b2, aff + 512);
  finalize_kernel<<<(C2 * N0 * B) / (4 * 256), 256, 0, stream>>>(out_nf, aff + 512);
  copy_xyz_kernel<<<(B * 3 * N0) / (4 * 256), 256, 0, stream>>>(xyz, out);
}

// Round 3
// 495.339 us; speedup vs baseline: 1.4990x; 1.1548x over previous
//
#include <hip/hip_runtime.h>
#include <hip/hip_bf16.h>

using bf16 = __hip_bfloat16;

constexpr int B  = 8;
constexpr int N0 = 8192;
constexpr int NS = 2048;
constexpr int CP = 512;
constexpr int CS = 256;
constexpr int C1 = 256;
constexpr int C2 = 256;
constexpr int K1 = CP + CS;          // 768
constexpr int COLS = B * N0;         // 65536
constexpr float BN_EPS = 1e-3f;
constexpr float SLOPE  = 0.01f;

typedef short  short8 __attribute__((ext_vector_type(8)));
typedef float  f32x4  __attribute__((ext_vector_type(4)));

typedef __attribute__((address_space(1))) unsigned int gas_uint;
typedef __attribute__((address_space(3))) unsigned int las_uint;

// manual RNE fp32->bf16 (no NaNs in this workload) and back
__device__ __forceinline__ unsigned short f2bu(float f) {
  unsigned int u = __float_as_uint(f);
  return (unsigned short)((u + 0x7fffu + ((u >> 16) & 1u)) >> 16);
}
__device__ __forceinline__ float bu2f(unsigned short v) {
  return __uint_as_float((unsigned int)v << 16);
}

// ---------------- prep: fp32 weights -> bf16 (row-major [M][K]), zero stats ----------------
__global__ __launch_bounds__(256) void prep_kernel(
    const float* __restrict__ W1, const float* __restrict__ W2,
    unsigned short* __restrict__ W1b, unsigned short* __restrict__ W2b,
    float* __restrict__ stats)
{
  int id = blockIdx.x * 256 + threadIdx.x;
  if (id < 1024) stats[id] = 0.0f;
  if (id < C1 * K1) W1b[id] = f2bu(W1[id]);
  if (id < C2 * C1) W2b[id] = f2bu(W2[id]);
}

// =======================================================================
// 3-NN, slice-split: block = 64 queries x 4 slices (256 thr).
// =======================================================================
__global__ __launch_bounds__(256) void knn_kernel(
    const float* __restrict__ xyz, const float* __restrict__ xyz_prev,
    float* __restrict__ wq, int* __restrict__ iq)
{
#pragma clang fp contract(off)
  __shared__ float4 sp[NS];                 // x,y,z,|p|^2  (32 KB)
  __shared__ float  md[4][64][3];
  __shared__ int    mi[4][64][3];
  const int b = blockIdx.y;
  const float* xp = xyz_prev + (size_t)b * 3 * NS;
  for (int j = threadIdx.x; j < NS; j += 256) {
    float x = xp[j], y = xp[NS + j], z = xp[2 * NS + j];
    sp[j] = make_float4(x, y, z, (x * x + y * y) + z * z);   // numpy association
  }
  __syncthreads();

  const int q  = threadIdx.x & 63;
  const int sl = threadIdx.x >> 6;
  const int n  = blockIdx.x * 64 + q;
  const float* xq = xyz + (size_t)b * 3 * N0;
  float qx = xq[n], qy = xq[N0 + n], qz = xq[2 * N0 + n];
  float qq = (qx * qx + qy * qy) + qz * qz;

  float d0 = 1e30f, d1 = 1e30f, d2 = 1e30f;
  int   i0 = 0, i1 = 0, i2 = 0;
  const int j0 = sl * (NS / 4), j1 = j0 + (NS / 4);
#pragma unroll 4
  for (int j = j0; j < j1; ++j) {
    float4 p = sp[j];
    float dot = (qx * p.x + qy * p.y) + qz * p.z;
    float d = (qq + p.w) - 2.0f * dot;      // numpy association
    if (d < d0)      { d2 = d1; i2 = i1; d1 = d0; i1 = i0; d0 = d; i0 = j; }
    else if (d < d1) { d2 = d1; i2 = i1; d1 = d;  i1 = j; }
    else if (d < d2) { d2 = d;  i2 = j; }
  }
  md[sl][q][0] = d0; md[sl][q][1] = d1; md[sl][q][2] = d2;
  mi[sl][q][0] = i0; mi[sl][q][1] = i1; mi[sl][q][2] = i2;
  __syncthreads();

  if (threadIdx.x < 64) {
    float e0 = 1e30f, e1 = 1e30f, e2 = 1e30f;
    int   k0 = 0, k1 = 0, k2 = 0;
#pragma unroll
    for (int s = 0; s < 4; ++s) {
#pragma unroll
      for (int t = 0; t < 3; ++t) {
        float d = md[s][q][t]; int ii = mi[s][q][t];
        if (d < e0)      { e2 = e1; k2 = k1; e1 = e0; k1 = k0; e0 = d; k0 = ii; }
        else if (d < e1) { e2 = e1; k2 = k1; e1 = d;  k1 = ii; }
        else if (d < e2) { e2 = d;  k2 = ii; }
      }
    }
    e0 = fmaxf(e0, 1e-10f); e1 = fmaxf(e1, 1e-10f); e2 = fmaxf(e2, 1e-10f);
    float v0 = 1.0f / (e0 + 1e-8f), v1 = 1.0f / (e1 + 1e-8f), v2 = 1.0f / (e2 + 1e-8f);
    float s = (v0 + v1) + v2;
    const int gi = (b * N0 + n) * 3;
    wq[gi + 0] = v0 / s; wq[gi + 1] = v1 / s; wq[gi + 2] = v2 / s;
    iq[gi + 0] = k0;     iq[gi + 1] = k1;     iq[gi + 2] = k2;
  }
}

// =======================================================================
// interp: LDS-gather. Block = (b, 16-channel group, n-half).
// =======================================================================
__global__ __launch_bounds__(256) void interp_kernel(
    const float* __restrict__ feat_prev, const int* __restrict__ iq,
    const float* __restrict__ wq, unsigned short* __restrict__ Xt)
{
  __shared__ unsigned short sf[16 * 2048];        // 64 KB
  const int bx = blockIdx.x;                      // 512 blocks
  const int b  = bx >> 6;
  const int cg = (bx >> 1) & 31;
  const int nh = bx & 1;
  const int c0 = cg * 16;
  const float* fp = feat_prev + ((size_t)b * CP + c0) * NS;

  for (int id = threadIdx.x; id < 8192; id += 256) {
    float4 v = reinterpret_cast<const float4*>(fp)[id];
    ushort4 o;
    o.x = f2bu(v.x); o.y = f2bu(v.y); o.z = f2bu(v.z); o.w = f2bu(v.w);
    *reinterpret_cast<ushort4*>(&sf[id * 4]) = o;
  }
  __syncthreads();

  const int nbase = nh * 4096;
  for (int it = 0; it < 16; ++it) {
    const int n    = nbase + it * 256 + threadIdx.x;
    const int gcol = b * N0 + n;
    const int gq   = gcol * 3;
    const int i0 = iq[gq], i1 = iq[gq + 1], i2 = iq[gq + 2];
    const float w0 = wq[gq], w1 = wq[gq + 1], w2 = wq[gq + 2];
    unsigned short outv[16];
#pragma unroll
    for (int c = 0; c < 16; ++c) {
      const unsigned short* row = &sf[c * 2048];
      float v = w0 * bu2f(row[i0]) + w1 * bu2f(row[i1]) + w2 * bu2f(row[i2]);
      outv[c] = f2bu(v);
    }
    unsigned short* dst = Xt + (size_t)gcol * K1 + c0;
    *reinterpret_cast<short8*>(dst)     = *reinterpret_cast<short8*>(&outv[0]);
    *reinterpret_cast<short8*>(dst + 8) = *reinterpret_cast<short8*>(&outv[8]);
  }
}

// =======================================================================
// skipT: transpose skip fp32 [c][n] -> Xt[n][512+c] bf16. Tile 64x64.
// =======================================================================
__global__ __launch_bounds__(256) void skipt_kernel(
    const float* __restrict__ skip, unsigned short* __restrict__ Xt)
{
  __shared__ float T[64][65];
  const int kt   = blockIdx.x & 3;
  const int ct   = blockIdx.x >> 2;
  const int col0 = ct * 64;
  const int b    = col0 >> 13;
  const int n0   = col0 & 8191;
  const float* src = skip + ((size_t)b * CS + kt * 64) * N0 + n0;

  for (int id = threadIdx.x; id < 1024; id += 256) {
    int r = id >> 4, q = id & 15;
    float4 v = *reinterpret_cast<const float4*>(src + (size_t)r * N0 + q * 4);
    T[r][q * 4 + 0] = v.x; T[r][q * 4 + 1] = v.y;
    T[r][q * 4 + 2] = v.z; T[r][q * 4 + 3] = v.w;
  }
  __syncthreads();
  for (int id = threadIdx.x; id < 512; id += 256) {
    int n = id >> 3, q = id & 7;
    alignas(16) unsigned short tmp[8];
#pragma unroll
    for (int j = 0; j < 8; ++j) tmp[j] = f2bu(T[q * 8 + j][n]);
    *reinterpret_cast<short8*>(Xt + (size_t)(col0 + n) * K1 + CP + kt * 64 + q * 8) =
        *reinterpret_cast<short8*>(tmp);
  }
}

// =======================================================================
// MFMA GEMM1 v3: BM=256 (full M) x BN=128, BK=64, 4 waves.
// A (W1b, 384 KB, L2-broadcast): direct global->VGPR fragments, NO LDS,
//   no barrier dependency -> barrier drains only 16 KB of B per step.
// B (Xt): dbuf LDS via global_load_lds + 1-ahead prefetch, chunk-XOR
//   swizzle (linear dest / inv-swz source / swz read -- proven R2, 0 confl).
// Xt read exactly once. Grid 512 = 2 blocks/CU, one round.
// =======================================================================
__global__ __launch_bounds__(256) void gemm1_kernel(
    const unsigned short* __restrict__ W1b, const unsigned short* __restrict__ Xt,
    unsigned short* __restrict__ Y1t, float* __restrict__ stats)
{
  __shared__ unsigned short Bs[2 * 128 * 64];   // 2 x 16 KB  [buf][n][k]

  const int tid   = threadIdx.x;
  const int gcol0 = blockIdx.x * 128;

  const int wv = tid >> 6, lane = tid & 63;
  const int wm = wv * 64;                  // wave's 64 M-rows (BM=256)
  const int qm = lane & 15, quad = lane >> 4;
  const int lr = lane >> 3, lc = lane & 7;
  const int sw_src = (lc ^ lr) * 8;        // inverse-swizzled source k-offset
  const int sw_rd  = qm & 7;               // read-side XOR key

  f32x4 acc[4][8];
#pragma unroll
  for (int i = 0; i < 4; ++i)
#pragma unroll
    for (int j = 0; j < 8; ++j) acc[i][j] = (f32x4){0.f, 0.f, 0.f, 0.f};

  auto stageB = [&](int kt, int buf) {
    const int kof = kt * 64 + sw_src;
#pragma unroll
    for (int t = 0; t < 4; ++t) {
      const int ch = wv * 4 + t;           // 0..15 (1 KB chunks)
      const int r  = ch * 8 + lr;          // n-row 0..127
      __builtin_amdgcn_global_load_lds(
          (const gas_uint*)(Xt + (size_t)(gcol0 + r) * K1 + kof),
          (las_uint*)(&Bs[buf * (128 * 64) + ch * 512]), 16, 0, 0);
    }
  };

  stageB(0, 0);
  __syncthreads();

  for (int kt = 0; kt < K1 / 64; ++kt) {
    const int cur = kt & 1;
    if (kt + 1 < K1 / 64) stageB(kt + 1, cur ^ 1);
    // A fragments straight from L2 (no staging, no drain dependency)
    short8 af[2][4];
#pragma unroll
    for (int h = 0; h < 2; ++h)
#pragma unroll
      for (int i = 0; i < 4; ++i)
        af[h][i] = *reinterpret_cast<const short8*>(
            W1b + (size_t)(wm + i * 16 + qm) * K1 + kt * 64 + h * 32 + quad * 8);
    const unsigned short* Bb = &Bs[cur * (128 * 64)];
#pragma unroll
    for (int h = 0; h < 2; ++h) {
      short8 bf[8];
#pragma unroll
      for (int j = 0; j < 8; ++j)
        bf[j] = *reinterpret_cast<const short8*>(
            &Bb[(j * 16 + qm) * 64 + ((h * 4 + quad) ^ sw_rd) * 8]);
#pragma unroll
      for (int i = 0; i < 4; ++i)
#pragma unroll
        for (int j = 0; j < 8; ++j)
          acc[i][j] = __builtin_amdgcn_mfma_f32_16x16x32_bf16(af[h][i], bf[j], acc[i][j], 0, 0, 0);
    }
    __syncthreads();   // prefetch landed + all reads of cur done
  }

  // epilogue: Y1t[n][c] bf16 (8 B contiguous) + BN1 stats
#pragma unroll
  for (int i = 0; i < 4; ++i) {
    const int mb = wm + i * 16 + quad * 4;
    float s[4] = {0.f, 0.f, 0.f, 0.f}, s2[4] = {0.f, 0.f, 0.f, 0.f};
#pragma unroll
    for (int j = 0; j < 8; ++j) {
      const int gc = gcol0 + j * 16 + qm;
      ushort4 o;
      o.x = f2bu(acc[i][j][0]); o.y = f2bu(acc[i][j][1]);
      o.z = f2bu(acc[i][j][2]); o.w = f2bu(acc[i][j][3]);
      *reinterpret_cast<ushort4*>(Y1t + (size_t)gc * C1 + mb) = o;
#pragma unroll
      for (int r = 0; r < 4; ++r) {
        float v = acc[i][j][r];
        s[r] += v; s2[r] += v * v;
      }
    }
#pragma unroll
    for (int m = 1; m < 16; m <<= 1) {
#pragma unroll
      for (int r = 0; r < 4; ++r) { s[r] += __shfl_xor(s[r], m); s2[r] += __shfl_xor(s2[r], m); }
    }
    if (qm == 0) {
#pragma unroll
      for (int r = 0; r < 4; ++r) {
        atomicAdd(&stats[mb + r], s[r]);
        atomicAdd(&stats[C1 + mb + r], s2[r]);
      }
    }
  }
}

// ---------------- affine: fold BN stats + gamma/beta into scale/shift ----------------
__global__ __launch_bounds__(256) void affine_kernel(
    const float* __restrict__ s, const float* __restrict__ g,
    const float* __restrict__ bb, float* __restrict__ a)
{
  int c = threadIdx.x;
  float inv = 1.0f / (float)COLS;
  float mean = s[c] * inv;
  float var  = s[C1 + c] * inv - mean * mean;
  float sc   = g[c] / sqrtf(var + BN_EPS);
  a[c]      = sc;
  a[C1 + c] = bb[c] - mean * sc;
}

// =======================================================================
// MFMA GEMM2 v3: BM=256 x BN=128, K=256 (4 steps), 4 waves.
// A (W2b, 128 KB): direct global->VGPR.
// B: reg-staged Y1t with FUSED bn1+LeakyReLU (replaces bn1_apply pass),
//    T14 split (loads early / xform+ds_write late), padded [128][72] LDS.
// fp32 out + BN2 stats.
// =======================================================================
__global__ __launch_bounds__(256) void gemm2_kernel(
    const unsigned short* __restrict__ W2b, const unsigned short* __restrict__ Y1t,
    const float* __restrict__ aff, float* __restrict__ out_nf,
    float* __restrict__ stats2)
{
  __shared__ unsigned short Bs[2][128][72];     // 2 x 18 KB, padded rows

  const int tid   = threadIdx.x;
  const int gcol0 = blockIdx.x * 128;
  const int b     = gcol0 >> 13;
  const int ncol0 = gcol0 & 8191;

  const int wv = tid >> 6, lane = tid & 63;
  const int wm = wv * 64;
  const int qm = lane & 15, quad = lane >> 4;
  const int sn = tid >> 1;                 // staging row 0..127
  const int sck = (tid & 1) * 4;           // staging chunk base (2 thr/row, 4 chunks each)

  f32x4 acc[4][8];
#pragma unroll
  for (int i = 0; i < 4; ++i)
#pragma unroll
    for (int j = 0; j < 8; ++j) acc[i][j] = (f32x4){0.f, 0.f, 0.f, 0.f};

  short8 breg[4];
  auto loadB = [&](int kt) {
#pragma unroll
    for (int t = 0; t < 4; ++t)
      breg[t] = *reinterpret_cast<const short8*>(
          Y1t + (size_t)(gcol0 + sn) * C1 + kt * 64 + (sck + t) * 8);
  };
  // affine+lrelu in fp32 on raw bf16 Y1, re-round to bf16 (== bn1_apply math)
  auto xformWrite = [&](int kt, int buf) {
#pragma unroll
    for (int t = 0; t < 4; ++t) {
      const int c0 = kt * 64 + (sck + t) * 8;
      float4 sc0 = *reinterpret_cast<const float4*>(aff + c0);
      float4 sc1 = *reinterpret_cast<const float4*>(aff + c0 + 4);
      float4 sh0 = *reinterpret_cast<const float4*>(aff + C1 + c0);
      float4 sh1 = *reinterpret_cast<const float4*>(aff + C1 + c0 + 4);
      alignas(16) unsigned short tmp[8];
#pragma unroll
      for (int j = 0; j < 4; ++j) {
        float v = bu2f((unsigned short)breg[t][j]) * (&sc0.x)[j] + (&sh0.x)[j];
        v = (v >= 0.f) ? v : SLOPE * v;
        tmp[j] = f2bu(v);
      }
#pragma unroll
      for (int j = 0; j < 4; ++j) {
        float v = bu2f((unsigned short)breg[t][4 + j]) * (&sc1.x)[j] + (&sh1.x)[j];
        v = (v >= 0.f) ? v : SLOPE * v;
        tmp[4 + j] = f2bu(v);
      }
      *reinterpret_cast<short8*>(&Bs[buf][sn][(sck + t) * 8]) =
          *reinterpret_cast<short8*>(tmp);
    }
  };

  loadB(0);
  xformWrite(0, 0);
  __syncthreads();

  for (int kt = 0; kt < C1 / 64; ++kt) {
    const int cur = kt & 1;
    if (kt + 1 < C1 / 64) loadB(kt + 1);   // issue early: latency hides under MFMA
    short8 af[2][4];
#pragma unroll
    for (int h = 0; h < 2; ++h)
#pragma unroll
      for (int i = 0; i < 4; ++i)
        af[h][i] = *reinterpret_cast<const short8*>(
            W2b + (size_t)(wm + i * 16 + qm) * C1 + kt * 64 + h * 32 + quad * 8);
#pragma unroll
    for (int h = 0; h < 2; ++h) {
      short8 bf[8];
#pragma unroll
      for (int j = 0; j < 8; ++j)
        bf[j] = *reinterpret_cast<const short8*>(
            &Bs[cur][j * 16 + qm][(h * 4 + quad) * 8]);
#pragma unroll
      for (int i = 0; i < 4; ++i)
#pragma unroll
        for (int j = 0; j < 8; ++j)
          acc[i][j] = __builtin_amdgcn_mfma_f32_16x16x32_bf16(af[h][i], bf[j], acc[i][j], 0, 0, 0);
    }
    if (kt + 1 < C1 / 64) xformWrite(kt + 1, cur ^ 1);  // write late (after compute)
    __syncthreads();
  }

  // epilogue: raw fp32 Y2 to out_nf [b][m][N0] + BN2 stats
#pragma unroll
  for (int i = 0; i < 4; ++i) {
    const int mb = wm + i * 16 + quad * 4;
    float s[4] = {0.f, 0.f, 0.f, 0.f}, s2[4] = {0.f, 0.f, 0.f, 0.f};
#pragma unroll
    for (int j = 0; j < 8; ++j) {
      const int col = ncol0 + j * 16 + qm;
#pragma unroll
      for (int r = 0; r < 4; ++r) {
        float v = acc[i][j][r];
        out_nf[((size_t)b * C2 + mb + r) * N0 + col] = v;
        s[r] += v; s2[r] += v * v;
      }
    }
#pragma unroll
    for (int m = 1; m < 16; m <<= 1) {
#pragma unroll
      for (int r = 0; r < 4; ++r) { s[r] += __shfl_xor(s[r], m); s2[r] += __shfl_xor(s2[r], m); }
    }
    if (qm == 0) {
#pragma unroll
      for (int r = 0; r < 4; ++r) {
        atomicAdd(&stats2[mb + r], s[r]);
        atomicAdd(&stats2[C2 + mb + r], s2[r]);
      }
    }
  }
}

// ---------------- finalize: in-place BN2 + LeakyReLU on out_nf (fp32) ----------------
__global__ __launch_bounds__(256) void finalize_kernel(float* __restrict__ nf,
                                                       const float* __restrict__ aff)
{
  int id4 = blockIdx.x * 256 + threadIdx.x;      // float4-granule index
  int e = id4 * 4;
  int c = (e % (C2 * N0)) / N0;
  float sc = aff[c], sh = aff[C1 + c];
  float4 v = reinterpret_cast<float4*>(nf)[id4];
  v.x = v.x * sc + sh; v.x = (v.x >= 0.f) ? v.x : SLOPE * v.x;
  v.y = v.y * sc + sh; v.y = (v.y >= 0.f) ? v.y : SLOPE * v.y;
  v.z = v.z * sc + sh; v.z = (v.z >= 0.f) ? v.z : SLOPE * v.z;
  v.w = v.w * sc + sh; v.w = (v.w >= 0.f) ? v.w : SLOPE * v.w;
  reinterpret_cast<float4*>(nf)[id4] = v;
}

// ---------------- copy xyz passthrough (fp32) ----------------
__global__ __launch_bounds__(256) void copy_xyz_kernel(const float* __restrict__ xyz,
                                                       float* __restrict__ out)
{
  int id = blockIdx.x * 256 + threadIdx.x;       // float4 granules, 12288 total
  reinterpret_cast<float4*>(out)[id] = reinterpret_cast<const float4*>(xyz)[id];
}

extern "C" void kernel_launch(void* const* d_in, const int* in_sizes, int n_in,
                              void* d_out, int out_size, void* d_ws, size_t ws_size,
                              hipStream_t stream)
{
  const float* xyz       = (const float*)d_in[0];
  const float* skip      = (const float*)d_in[1];
  const float* xyz_prev  = (const float*)d_in[2];
  const float* feat_prev = (const float*)d_in[3];
  const float* W1        = (const float*)d_in[4];
  const float* g1        = (const float*)d_in[5];
  const float* b1        = (const float*)d_in[6];
  const float* W2        = (const float*)d_in[7];
  const float* g2        = (const float*)d_in[8];
  const float* b2        = (const float*)d_in[9];

  float* out    = (float*)d_out;
  float* out_nf = out + (size_t)B * 3 * N0;      // [B][C2][N0] fp32

  char* ws = (char*)d_ws;
  float*          wq    = (float*)(ws + 0);                 //   786432 B
  int*            iq    = (int*)  (ws + 786432);            //   786432 B
  unsigned short* W1b   = (unsigned short*)(ws + 1572864);  //   393216 B
  unsigned short* W2b   = (unsigned short*)(ws + 1966080);  //   131072 B
  float*          stats = (float*)(ws + 2097152);           //     4096 B
  float*          aff   = (float*)(ws + 2101248);           //     4096 B
  unsigned short* Y1t   = (unsigned short*)(ws + 2105344);  // 33554432 B  [COLS][C1]
  unsigned short* Xt    = (unsigned short*)(ws + 35659776); // 100663296 B [COLS][K1]
  // total: 136,323,072 B

  prep_kernel<<<768, 256, 0, stream>>>(W1, W2, W1b, W2b, stats);
  knn_kernel<<<dim3(N0 / 64, B), 256, 0, stream>>>(xyz, xyz_prev, wq, iq);
  interp_kernel<<<512, 256, 0, stream>>>(feat_prev, iq, wq, Xt);
  skipt_kernel<<<4096, 256, 0, stream>>>(skip, Xt);
  gemm1_kernel<<<COLS / 128, 256, 0, stream>>>(W1b, Xt, Y1t, stats);
  affine_kernel<<<1, 256, 0, stream>>>(stats, g1, b1, aff);
  gemm2_kernel<<<COLS / 128, 256, 0, stream>>>(W2b, Y1t, aff, out_nf, stats + 512);
  affine_kernel<<<1, 256, 0, stream>>>(stats + 512, g2, b2, aff + 512);
  finalize_kernel<<<(C2 * N0 * B) / (4 * 256), 256, 0, stream>>>(out_nf, aff + 512);
  copy_xyz_kernel<<<(B * 3 * N0) / (4 * 256), 256, 0, stream>>>(xyz, out);
}

// Round 4
// 477.603 us; speedup vs baseline: 1.5547x; 1.0371x over previous
//
#include <hip/hip_runtime.h>
#include <hip/hip_bf16.h>

using bf16 = __hip_bfloat16;

constexpr int B  = 8;
constexpr int N0 = 8192;
constexpr int NS = 2048;
constexpr int CP = 512;
constexpr int CS = 256;
constexpr int C1 = 256;
constexpr int C2 = 256;
constexpr int K1 = CP + CS;          // 768
constexpr int COLS = B * N0;         // 65536
constexpr float BN_EPS = 1e-3f;
constexpr float SLOPE  = 0.01f;

typedef short  short8 __attribute__((ext_vector_type(8)));
typedef float  f32x4  __attribute__((ext_vector_type(4)));

typedef __attribute__((address_space(1))) unsigned int gas_uint;
typedef __attribute__((address_space(3))) unsigned int las_uint;

// manual RNE fp32->bf16 (no NaNs in this workload) and back
__device__ __forceinline__ unsigned short f2bu(float f) {
  unsigned int u = __float_as_uint(f);
  return (unsigned short)((u + 0x7fffu + ((u >> 16) & 1u)) >> 16);
}
__device__ __forceinline__ float bu2f(unsigned short v) {
  return __uint_as_float((unsigned int)v << 16);
}

// ---------------- prep: fp32 weights -> bf16 (row-major [M][K]), zero stats ----------------
__global__ __launch_bounds__(256) void prep_kernel(
    const float* __restrict__ W1, const float* __restrict__ W2,
    unsigned short* __restrict__ W1b, unsigned short* __restrict__ W2b,
    float* __restrict__ stats)
{
  int id = blockIdx.x * 256 + threadIdx.x;
  if (id < 1024) stats[id] = 0.0f;
  if (id < C1 * K1) W1b[id] = f2bu(W1[id]);
  if (id < C2 * C1) W2b[id] = f2bu(W2[id]);
}

// =======================================================================
// 3-NN, slice-split: block = 64 queries x 4 slices (256 thr).
// =======================================================================
__global__ __launch_bounds__(256) void knn_kernel(
    const float* __restrict__ xyz, const float* __restrict__ xyz_prev,
    float* __restrict__ wq, int* __restrict__ iq)
{
#pragma clang fp contract(off)
  __shared__ float4 sp[NS];                 // x,y,z,|p|^2  (32 KB)
  __shared__ float  md[4][64][3];
  __shared__ int    mi[4][64][3];
  const int b = blockIdx.y;
  const float* xp = xyz_prev + (size_t)b * 3 * NS;
  for (int j = threadIdx.x; j < NS; j += 256) {
    float x = xp[j], y = xp[NS + j], z = xp[2 * NS + j];
    sp[j] = make_float4(x, y, z, (x * x + y * y) + z * z);   // numpy association
  }
  __syncthreads();

  const int q  = threadIdx.x & 63;
  const int sl = threadIdx.x >> 6;
  const int n  = blockIdx.x * 64 + q;
  const float* xq = xyz + (size_t)b * 3 * N0;
  float qx = xq[n], qy = xq[N0 + n], qz = xq[2 * N0 + n];
  float qq = (qx * qx + qy * qy) + qz * qz;

  float d0 = 1e30f, d1 = 1e30f, d2 = 1e30f;
  int   i0 = 0, i1 = 0, i2 = 0;
  const int j0 = sl * (NS / 4), j1 = j0 + (NS / 4);
#pragma unroll 4
  for (int j = j0; j < j1; ++j) {
    float4 p = sp[j];
    float dot = (qx * p.x + qy * p.y) + qz * p.z;
    float d = (qq + p.w) - 2.0f * dot;      // numpy association
    if (d < d0)      { d2 = d1; i2 = i1; d1 = d0; i1 = i0; d0 = d; i0 = j; }
    else if (d < d1) { d2 = d1; i2 = i1; d1 = d;  i1 = j; }
    else if (d < d2) { d2 = d;  i2 = j; }
  }
  md[sl][q][0] = d0; md[sl][q][1] = d1; md[sl][q][2] = d2;
  mi[sl][q][0] = i0; mi[sl][q][1] = i1; mi[sl][q][2] = i2;
  __syncthreads();

  if (threadIdx.x < 64) {
    float e0 = 1e30f, e1 = 1e30f, e2 = 1e30f;
    int   k0 = 0, k1 = 0, k2 = 0;
#pragma unroll
    for (int s = 0; s < 4; ++s) {
#pragma unroll
      for (int t = 0; t < 3; ++t) {
        float d = md[s][q][t]; int ii = mi[s][q][t];
        if (d < e0)      { e2 = e1; k2 = k1; e1 = e0; k1 = k0; e0 = d; k0 = ii; }
        else if (d < e1) { e2 = e1; k2 = k1; e1 = d;  k1 = ii; }
        else if (d < e2) { e2 = d;  k2 = ii; }
      }
    }
    e0 = fmaxf(e0, 1e-10f); e1 = fmaxf(e1, 1e-10f); e2 = fmaxf(e2, 1e-10f);
    float v0 = 1.0f / (e0 + 1e-8f), v1 = 1.0f / (e1 + 1e-8f), v2 = 1.0f / (e2 + 1e-8f);
    float s = (v0 + v1) + v2;
    const int gi = (b * N0 + n) * 3;
    wq[gi + 0] = v0 / s; wq[gi + 1] = v1 / s; wq[gi + 2] = v2 / s;
    iq[gi + 0] = k0;     iq[gi + 1] = k1;     iq[gi + 2] = k2;
  }
}

// =======================================================================
// interp: LDS-gather. Block = (b, 16-channel group, n-half).
// =======================================================================
__global__ __launch_bounds__(256) void interp_kernel(
    const float* __restrict__ feat_prev, const int* __restrict__ iq,
    const float* __restrict__ wq, unsigned short* __restrict__ Xt)
{
  __shared__ unsigned short sf[16 * 2048];        // 64 KB
  const int bx = blockIdx.x;                      // 512 blocks
  const int b  = bx >> 6;
  const int cg = (bx >> 1) & 31;
  const int nh = bx & 1;
  const int c0 = cg * 16;
  const float* fp = feat_prev + ((size_t)b * CP + c0) * NS;

  for (int id = threadIdx.x; id < 8192; id += 256) {
    float4 v = reinterpret_cast<const float4*>(fp)[id];
    ushort4 o;
    o.x = f2bu(v.x); o.y = f2bu(v.y); o.z = f2bu(v.z); o.w = f2bu(v.w);
    *reinterpret_cast<ushort4*>(&sf[id * 4]) = o;
  }
  __syncthreads();

  const int nbase = nh * 4096;
  for (int it = 0; it < 16; ++it) {
    const int n    = nbase + it * 256 + threadIdx.x;
    const int gcol = b * N0 + n;
    const int gq   = gcol * 3;
    const int i0 = iq[gq], i1 = iq[gq + 1], i2 = iq[gq + 2];
    const float w0 = wq[gq], w1 = wq[gq + 1], w2 = wq[gq + 2];
    unsigned short outv[16];
#pragma unroll
    for (int c = 0; c < 16; ++c) {
      const unsigned short* row = &sf[c * 2048];
      float v = w0 * bu2f(row[i0]) + w1 * bu2f(row[i1]) + w2 * bu2f(row[i2]);
      outv[c] = f2bu(v);
    }
    unsigned short* dst = Xt + (size_t)gcol * K1 + c0;
    *reinterpret_cast<short8*>(dst)     = *reinterpret_cast<short8*>(&outv[0]);
    *reinterpret_cast<short8*>(dst + 8) = *reinterpret_cast<short8*>(&outv[8]);
  }
}

// =======================================================================
// skipT: transpose skip fp32 [c][n] -> Xt[n][512+c] bf16. Tile 64x64.
// =======================================================================
__global__ __launch_bounds__(256) void skipt_kernel(
    const float* __restrict__ skip, unsigned short* __restrict__ Xt)
{
  __shared__ float T[64][65];
  const int kt   = blockIdx.x & 3;
  const int ct   = blockIdx.x >> 2;
  const int col0 = ct * 64;
  const int b    = col0 >> 13;
  const int n0   = col0 & 8191;
  const float* src = skip + ((size_t)b * CS + kt * 64) * N0 + n0;

  for (int id = threadIdx.x; id < 1024; id += 256) {
    int r = id >> 4, q = id & 15;
    float4 v = *reinterpret_cast<const float4*>(src + (size_t)r * N0 + q * 4);
    T[r][q * 4 + 0] = v.x; T[r][q * 4 + 1] = v.y;
    T[r][q * 4 + 2] = v.z; T[r][q * 4 + 3] = v.w;
  }
  __syncthreads();
  for (int id = threadIdx.x; id < 512; id += 256) {
    int n = id >> 3, q = id & 7;
    alignas(16) unsigned short tmp[8];
#pragma unroll
    for (int j = 0; j < 8; ++j) tmp[j] = f2bu(T[q * 8 + j][n]);
    *reinterpret_cast<short8*>(Xt + (size_t)(col0 + n) * K1 + CP + kt * 64 + q * 8) =
        *reinterpret_cast<short8*>(tmp);
  }
}

// =======================================================================
// MFMA GEMM1 v4: BM=256 x BN=128, BK=64, 4 waves.
// FIX vs v3: vmcnt retires IN ORDER, so A-loads issued after the B
// prefetch forced vmcnt(0) (full drain) before the MFMAs -> serial loop.
// Now A fragments are DOUBLE-BUFFERED in registers: phase k issues
// stageB(k+1) + loadA(k+1) and computes with af_cur, which was drained
// by the PREVIOUS barrier -> MFMAs need no vmcnt wait at all; the only
// drain is at the end-of-phase barrier, after the compute.
// =======================================================================
__global__ __launch_bounds__(256, 2) void gemm1_kernel(
    const unsigned short* __restrict__ W1b, const unsigned short* __restrict__ Xt,
    unsigned short* __restrict__ Y1t, float* __restrict__ stats)
{
  __shared__ unsigned short Bs[2 * 128 * 64];   // 2 x 16 KB  [buf][n][k]

  const int tid   = threadIdx.x;
  const int gcol0 = blockIdx.x * 128;

  const int wv = tid >> 6, lane = tid & 63;
  const int wm = wv * 64;                  // wave's 64 M-rows (BM=256)
  const int qm = lane & 15, quad = lane >> 4;
  const int lr = lane >> 3, lc = lane & 7;
  const int sw_src = (lc ^ lr) * 8;        // inverse-swizzled source k-offset
  const int sw_rd  = qm & 7;               // read-side XOR key

  f32x4 acc[4][8];
#pragma unroll
  for (int i = 0; i < 4; ++i)
#pragma unroll
    for (int j = 0; j < 8; ++j) acc[i][j] = (f32x4){0.f, 0.f, 0.f, 0.f};

  auto stageB = [&](int kt, int buf) {
    const int kof = kt * 64 + sw_src;
#pragma unroll
    for (int t = 0; t < 4; ++t) {
      const int ch = wv * 4 + t;           // 0..15 (1 KB chunks)
      const int r  = ch * 8 + lr;          // n-row 0..127
      __builtin_amdgcn_global_load_lds(
          (const gas_uint*)(Xt + (size_t)(gcol0 + r) * K1 + kof),
          (las_uint*)(&Bs[buf * (128 * 64) + ch * 512]), 16, 0, 0);
    }
  };
  auto loadA = [&](int kt, short8 (&af)[2][4]) {
#pragma unroll
    for (int h = 0; h < 2; ++h)
#pragma unroll
      for (int i = 0; i < 4; ++i)
        af[h][i] = *reinterpret_cast<const short8*>(
            W1b + (size_t)(wm + i * 16 + qm) * K1 + kt * 64 + h * 32 + quad * 8);
  };
  auto compute = [&](const short8 (&af)[2][4], int buf) {
    const unsigned short* Bb = &Bs[buf * (128 * 64)];
#pragma unroll
    for (int h = 0; h < 2; ++h) {
      short8 bf[8];
#pragma unroll
      for (int j = 0; j < 8; ++j)
        bf[j] = *reinterpret_cast<const short8*>(
            &Bb[(j * 16 + qm) * 64 + ((h * 4 + quad) ^ sw_rd) * 8]);
#pragma unroll
      for (int i = 0; i < 4; ++i)
#pragma unroll
        for (int j = 0; j < 8; ++j)
          acc[i][j] = __builtin_amdgcn_mfma_f32_16x16x32_bf16(af[h][i], bf[j], acc[i][j], 0, 0, 0);
    }
  };

  short8 afA[2][4], afB[2][4];
  loadA(0, afA);
  stageB(0, 0);
  __syncthreads();                          // afA + Bs[0] ready

  for (int kt = 0; kt < K1 / 64; kt += 2) {
    stageB(kt + 1, 1);                      // prefetch flies during compute
    loadA(kt + 1, afB);
    compute(afA, 0);                        // no vmcnt dependency
    __syncthreads();                        // drain happens AFTER compute
    if (kt + 2 < K1 / 64) { stageB(kt + 2, 0); loadA(kt + 2, afA); }
    compute(afB, 1);
    if (kt + 2 < K1 / 64) __syncthreads();
  }

  // epilogue: Y1t[n][c] bf16 (8 B contiguous) + BN1 stats
#pragma unroll
  for (int i = 0; i < 4; ++i) {
    const int mb = wm + i * 16 + quad * 4;
    float s[4] = {0.f, 0.f, 0.f, 0.f}, s2[4] = {0.f, 0.f, 0.f, 0.f};
#pragma unroll
    for (int j = 0; j < 8; ++j) {
      const int gc = gcol0 + j * 16 + qm;
      ushort4 o;
      o.x = f2bu(acc[i][j][0]); o.y = f2bu(acc[i][j][1]);
      o.z = f2bu(acc[i][j][2]); o.w = f2bu(acc[i][j][3]);
      *reinterpret_cast<ushort4*>(Y1t + (size_t)gc * C1 + mb) = o;
#pragma unroll
      for (int r = 0; r < 4; ++r) {
        float v = acc[i][j][r];
        s[r] += v; s2[r] += v * v;
      }
    }
#pragma unroll
    for (int m = 1; m < 16; m <<= 1) {
#pragma unroll
      for (int r = 0; r < 4; ++r) { s[r] += __shfl_xor(s[r], m); s2[r] += __shfl_xor(s2[r], m); }
    }
    if (qm == 0) {
#pragma unroll
      for (int r = 0; r < 4; ++r) {
        atomicAdd(&stats[mb + r], s[r]);
        atomicAdd(&stats[C1 + mb + r], s2[r]);
      }
    }
  }
}

// ---------------- affine: fold BN stats + gamma/beta into scale/shift ----------------
__global__ __launch_bounds__(256) void affine_kernel(
    const float* __restrict__ s, const float* __restrict__ g,
    const float* __restrict__ bb, float* __restrict__ a)
{
  int c = threadIdx.x;
  float inv = 1.0f / (float)COLS;
  float mean = s[c] * inv;
  float var  = s[C1 + c] * inv - mean * mean;
  float sc   = g[c] / sqrtf(var + BN_EPS);
  a[c]      = sc;
  a[C1 + c] = bb[c] - mean * sc;
}

// =======================================================================
// MFMA GEMM2 v4: BM=256 x BN=128, K=256 (4 steps), 4 waves.
// loadA issued FIRST each phase (oldest in vmcnt queue) -> MFMA's wait
// leaves loadB(k+1) in flight; xformWrite's breg wait lands after the
// MFMAs. B reg-staged with fused bn1+LeakyReLU, padded [128][72] LDS dbuf.
// =======================================================================
__global__ __launch_bounds__(256, 2) void gemm2_kernel(
    const unsigned short* __restrict__ W2b, const unsigned short* __restrict__ Y1t,
    const float* __restrict__ aff, float* __restrict__ out_nf,
    float* __restrict__ stats2)
{
  __shared__ unsigned short Bs[2][128][72];     // 2 x 18 KB, padded rows

  const int tid   = threadIdx.x;
  const int gcol0 = blockIdx.x * 128;
  const int b     = gcol0 >> 13;
  const int ncol0 = gcol0 & 8191;

  const int wv = tid >> 6, lane = tid & 63;
  const int wm = wv * 64;
  const int qm = lane & 15, quad = lane >> 4;
  const int sn = tid >> 1;                 // staging row 0..127
  const int sck = (tid & 1) * 4;           // staging chunk base (2 thr/row)

  f32x4 acc[4][8];
#pragma unroll
  for (int i = 0; i < 4; ++i)
#pragma unroll
    for (int j = 0; j < 8; ++j) acc[i][j] = (f32x4){0.f, 0.f, 0.f, 0.f};

  short8 af[2][4];
  short8 breg[4];
  auto loadA = [&](int kt) {
#pragma unroll
    for (int h = 0; h < 2; ++h)
#pragma unroll
      for (int i = 0; i < 4; ++i)
        af[h][i] = *reinterpret_cast<const short8*>(
            W2b + (size_t)(wm + i * 16 + qm) * C1 + kt * 64 + h * 32 + quad * 8);
  };
  auto loadB = [&](int kt) {
#pragma unroll
    for (int t = 0; t < 4; ++t)
      breg[t] = *reinterpret_cast<const short8*>(
          Y1t + (size_t)(gcol0 + sn) * C1 + kt * 64 + (sck + t) * 8);
  };
  // affine+lrelu in fp32 on raw bf16 Y1, re-round to bf16
  auto xformWrite = [&](int kt, int buf) {
#pragma unroll
    for (int t = 0; t < 4; ++t) {
      const int c0 = kt * 64 + (sck + t) * 8;
      float4 sc0 = *reinterpret_cast<const float4*>(aff + c0);
      float4 sc1 = *reinterpret_cast<const float4*>(aff + c0 + 4);
      float4 sh0 = *reinterpret_cast<const float4*>(aff + C1 + c0);
      float4 sh1 = *reinterpret_cast<const float4*>(aff + C1 + c0 + 4);
      alignas(16) unsigned short tmp[8];
#pragma unroll
      for (int j = 0; j < 4; ++j) {
        float v = bu2f((unsigned short)breg[t][j]) * (&sc0.x)[j] + (&sh0.x)[j];
        v = (v >= 0.f) ? v : SLOPE * v;
        tmp[j] = f2bu(v);
      }
#pragma unroll
      for (int j = 0; j < 4; ++j) {
        float v = bu2f((unsigned short)breg[t][4 + j]) * (&sc1.x)[j] + (&sh1.x)[j];
        v = (v >= 0.f) ? v : SLOPE * v;
        tmp[4 + j] = f2bu(v);
      }
      *reinterpret_cast<short8*>(&Bs[buf][sn][(sck + t) * 8]) =
          *reinterpret_cast<short8*>(tmp);
    }
  };
  auto compute = [&](int buf) {
#pragma unroll
    for (int h = 0; h < 2; ++h) {
      short8 bf[8];
#pragma unroll
      for (int j = 0; j < 8; ++j)
        bf[j] = *reinterpret_cast<const short8*>(
            &Bs[buf][j * 16 + qm][(h * 4 + quad) * 8]);
#pragma unroll
      for (int i = 0; i < 4; ++i)
#pragma unroll
        for (int j = 0; j < 8; ++j)
          acc[i][j] = __builtin_amdgcn_mfma_f32_16x16x32_bf16(af[h][i], bf[j], acc[i][j], 0, 0, 0);
    }
  };

  loadB(0);
  xformWrite(0, 0);
  __syncthreads();

  for (int kt = 0; kt < C1 / 64; ++kt) {
    loadA(kt);                              // oldest in queue -> partial wait
    if (kt + 1 < C1 / 64) loadB(kt + 1);    // stays in flight through MFMAs
    compute(kt & 1);
    if (kt + 1 < C1 / 64) {
      xformWrite(kt + 1, (kt + 1) & 1);     // breg wait lands after compute
      __syncthreads();
    }
  }

  // epilogue: raw fp32 Y2 to out_nf [b][m][N0] + BN2 stats
#pragma unroll
  for (int i = 0; i < 4; ++i) {
    const int mb = wm + i * 16 + quad * 4;
    float s[4] = {0.f, 0.f, 0.f, 0.f}, s2[4] = {0.f, 0.f, 0.f, 0.f};
#pragma unroll
    for (int j = 0; j < 8; ++j) {
      const int col = ncol0 + j * 16 + qm;
#pragma unroll
      for (int r = 0; r < 4; ++r) {
        float v = acc[i][j][r];
        out_nf[((size_t)b * C2 + mb + r) * N0 + col] = v;
        s[r] += v; s2[r] += v * v;
      }
    }
#pragma unroll
    for (int m = 1; m < 16; m <<= 1) {
#pragma unroll
      for (int r = 0; r < 4; ++r) { s[r] += __shfl_xor(s[r], m); s2[r] += __shfl_xor(s2[r], m); }
    }
    if (qm == 0) {
#pragma unroll
      for (int r = 0; r < 4; ++r) {
        atomicAdd(&stats2[mb + r], s[r]);
        atomicAdd(&stats2[C2 + mb + r], s2[r]);
      }
    }
  }
}

// ---------------- finalize: in-place BN2 + LeakyReLU on out_nf (fp32) ----------------
__global__ __launch_bounds__(256) void finalize_kernel(float* __restrict__ nf,
                                                       const float* __restrict__ aff)
{
  int id4 = blockIdx.x * 256 + threadIdx.x;      // float4-granule index
  int e = id4 * 4;
  int c = (e % (C2 * N0)) / N0;
  float sc = aff[c], sh = aff[C1 + c];
  float4 v = reinterpret_cast<float4*>(nf)[id4];
  v.x = v.x * sc + sh; v.x = (v.x >= 0.f) ? v.x : SLOPE * v.x;
  v.y = v.y * sc + sh; v.y = (v.y >= 0.f) ? v.y : SLOPE * v.y;
  v.z = v.z * sc + sh; v.z = (v.z >= 0.f) ? v.z : SLOPE * v.z;
  v.w = v.w * sc + sh; v.w = (v.w >= 0.f) ? v.w : SLOPE * v.w;
  reinterpret_cast<float4*>(nf)[id4] = v;
}

// ---------------- copy xyz passthrough (fp32) ----------------
__global__ __launch_bounds__(256) void copy_xyz_kernel(const float* __restrict__ xyz,
                                                       float* __restrict__ out)
{
  int id = blockIdx.x * 256 + threadIdx.x;       // float4 granules, 12288 total
  reinterpret_cast<float4*>(out)[id] = reinterpret_cast<const float4*>(xyz)[id];
}

extern "C" void kernel_launch(void* const* d_in, const int* in_sizes, int n_in,
                              void* d_out, int out_size, void* d_ws, size_t ws_size,
                              hipStream_t stream)
{
  const float* xyz       = (const float*)d_in[0];
  const float* skip      = (const float*)d_in[1];
  const float* xyz_prev  = (const float*)d_in[2];
  const float* feat_prev = (const float*)d_in[3];
  const float* W1        = (const float*)d_in[4];
  const float* g1        = (const float*)d_in[5];
  const float* b1        = (const float*)d_in[6];
  const float* W2        = (const float*)d_in[7];
  const float* g2        = (const float*)d_in[8];
  const float* b2        = (const float*)d_in[9];

  float* out    = (float*)d_out;
  float* out_nf = out + (size_t)B * 3 * N0;      // [B][C2][N0] fp32

  char* ws = (char*)d_ws;
  float*          wq    = (float*)(ws + 0);                 //   786432 B
  int*            iq    = (int*)  (ws + 786432);            //   786432 B
  unsigned short* W1b   = (unsigned short*)(ws + 1572864);  //   393216 B
  unsigned short* W2b   = (unsigned short*)(ws + 1966080);  //   131072 B
  float*          stats = (float*)(ws + 2097152);           //     4096 B
  float*          aff   = (float*)(ws + 2101248);           //     4096 B
  unsigned short* Y1t   = (unsigned short*)(ws + 2105344);  // 33554432 B  [COLS][C1]
  unsigned short* Xt    = (unsigned short*)(ws + 35659776); // 100663296 B [COLS][K1]
  // total: 136,323,072 B

  prep_kernel<<<768, 256, 0, stream>>>(W1, W2, W1b, W2b, stats);
  knn_kernel<<<dim3(N0 / 64, B), 256, 0, stream>>>(xyz, xyz_prev, wq, iq);
  interp_kernel<<<512, 256, 0, stream>>>(feat_prev, iq, wq, Xt);
  skipt_kernel<<<4096, 256, 0, stream>>>(skip, Xt);
  gemm1_kernel<<<COLS / 128, 256, 0, stream>>>(W1b, Xt, Y1t, stats);
  affine_kernel<<<1, 256, 0, stream>>>(stats, g1, b1, aff);
  gemm2_kernel<<<COLS / 128, 256, 0, stream>>>(W2b, Y1t, aff, out_nf, stats + 512);
  affine_kernel<<<1, 256, 0, stream>>>(stats + 512, g2, b2, aff + 512);
  finalize_kernel<<<(C2 * N0 * B) / (4 * 256), 256, 0, stream>>>(out_nf, aff + 512);
  copy_xyz_kernel<<<(B * 3 * N0) / (4 * 256), 256, 0, stream>>>(xyz, out);
}